// Round 1
// baseline (4604.324 us; speedup 1.0000x reference)
//
#include <hip/hip_runtime.h>
#include <math.h>

// ---------------------------------------------------------------------------
// UKF(2048) collapses analytically to a linear Kalman update (see analysis):
//   x_pred = A x + B u + c1 ;  Pk = P + Q
//   T = C Pk ; Py = T C^T + R
//   Z = Py^{-1} T (Newton-Schulz) ; z = Py^{-1} r ; r = y - (C x_pred + D u + c2)
//   x_out = x_pred + T^T z ;  P_out = Pk - T^T Z
// ---------------------------------------------------------------------------

#define BM 128
#define BN 128
#define BK 16
#define LDT 132   // padded LDS leading dim (16B-aligned rows, conflict-light)

// out[row] = dot(A[row,:], v) + (addv ? addv[row] : 0)
__global__ void matvec_kernel(const float* __restrict__ A, const float* __restrict__ v,
                              const float* __restrict__ addv, float* __restrict__ out, int n)
{
    int wid  = threadIdx.x >> 6;
    int lane = threadIdx.x & 63;
    int row  = blockIdx.x * 4 + wid;
    if (row >= n) return;
    const float* arow = A + (size_t)row * n;
    float s = 0.f;
    for (int j = lane; j < n; j += 64) s += arow[j] * v[j];
#pragma unroll
    for (int off = 32; off > 0; off >>= 1) s += __shfl_down(s, off);
    if (lane == 0) out[row] = s + (addv ? addv[row] : 0.f);
}

__global__ void vec_sub_kernel(const float* __restrict__ a, const float* __restrict__ b,
                               float* __restrict__ o, int n)
{
    int i = blockIdx.x * 256 + threadIdx.x;
    if (i < n) o[i] = a[i] - b[i];
}

__global__ void vec_fill_kernel(float* __restrict__ o, float val, int n)
{
    int i = blockIdx.x * 256 + threadIdx.x;
    if (i < n) o[i] = val;
}

__global__ void addmat_kernel(const float* __restrict__ a, const float* __restrict__ b,
                              float* __restrict__ o, int n4)
{
    int i = blockIdx.x * 256 + threadIdx.x;
    if (i < n4) {
        float4 x = ((const float4*)a)[i];
        float4 y = ((const float4*)b)[i];
        ((float4*)o)[i] = make_float4(x.x + y.x, x.y + y.y, x.z + y.z, x.w + y.w);
    }
}

__global__ void normsq_kernel(const float* __restrict__ v, float* __restrict__ out, int n)
{
    __shared__ float sm[256];
    float s = 0.f;
    for (int i = threadIdx.x; i < n; i += 256) { float x = v[i]; s += x * x; }
    sm[threadIdx.x] = s;
    __syncthreads();
    for (int w = 128; w > 0; w >>= 1) {
        if (threadIdx.x < w) sm[threadIdx.x] += sm[threadIdx.x + w];
        __syncthreads();
    }
    if (threadIdx.x == 0) out[0] = sm[0];
}

// alpha = 2 / (1.3 * lambda_max_est), lambda = ||v10|| / ||v9||
__global__ void alpha_kernel(const float* __restrict__ ns9, const float* __restrict__ ns10,
                             float* __restrict__ alpha)
{
    float lam = sqrtf(ns10[0] / ns9[0]);
    alpha[0] = 2.0f / (1.3f * lam);
}

__global__ void eye_kernel(float* __restrict__ X, const float* __restrict__ alpha, int n)
{
    float a = alpha[0];
    size_t total = (size_t)n * n;
    for (size_t idx = (size_t)blockIdx.x * blockDim.x + threadIdx.x; idx < total;
         idx += (size_t)gridDim.x * blockDim.x) {
        int i = (int)(idx / n), j = (int)(idx % n);
        X[idx] = (i == j) ? a : 0.f;
    }
}

// parts[c][i] = sum_{k in chunk c} T[k][i] * zv[k]   (chunk = 128 k's)
__global__ void tTv_partial_kernel(const float* __restrict__ T, const float* __restrict__ zv,
                                   float* __restrict__ parts, int n)
{
    int i = blockIdx.x * 256 + threadIdx.x;
    int c = blockIdx.y;
    float s = 0.f;
    int k0 = c * 128;
    for (int k = k0; k < k0 + 128; ++k) s += T[(size_t)k * n + i] * zv[k];
    parts[(size_t)c * n + i] = s;
}

__global__ void xout_final_kernel(const float* __restrict__ xp, const float* __restrict__ parts,
                                  float* __restrict__ xout, int n)
{
    int i = blockIdx.x * 256 + threadIdx.x;
    float s = xp[i];
    for (int c = 0; c < 16; ++c) s += parts[(size_t)c * n + i];
    xout[i] = s;
}

// O = op(MODE){ A_l @ B_l } where A_l = TA? A^T : A ; B_l = TB? B^T : B
// MODE 0: O = AB ; 1: O = AB + Dm ; 2: O = Dm - AB ; 3: O = 2I - AB
template <int TA, int TB, int MODE>
__global__ __launch_bounds__(256) void gemm_kernel(const float* __restrict__ A,
                                                   const float* __restrict__ B,
                                                   const float* Dm, float* O, int n)
{
    __shared__ float As[BK][LDT];
    __shared__ float Bs[BK][LDT];
    const int t  = threadIdx.x;
    const int bx = blockIdx.x, by = blockIdx.y;
    const int m0 = by * BM, n0 = bx * BN;
    const int tx = t & 15, ty = t >> 4;

    float acc[8][8] = {};

    for (int k0 = 0; k0 < n; k0 += BK) {
        // ---- stage A tile: As[k][m] = A_l[m0+m][k0+k]
        if (TA == 0) {
#pragma unroll
            for (int j = 0; j < 2; ++j) {
                int fi = t + 256 * j;
                int m = fi >> 2, kq = fi & 3;
                const float4 av = *(const float4*)&A[(size_t)(m0 + m) * n + k0 + 4 * kq];
                As[4 * kq + 0][m] = av.x; As[4 * kq + 1][m] = av.y;
                As[4 * kq + 2][m] = av.z; As[4 * kq + 3][m] = av.w;
            }
        } else {
#pragma unroll
            for (int j = 0; j < 2; ++j) {
                int fi = t + 256 * j;
                int k = fi >> 5, mq = fi & 31;
                *(float4*)&As[k][4 * mq] = *(const float4*)&A[(size_t)(k0 + k) * n + m0 + 4 * mq];
            }
        }
        // ---- stage B tile: Bs[k][nn] = B_l[k0+k][n0+nn]
        if (TB == 0) {
#pragma unroll
            for (int j = 0; j < 2; ++j) {
                int fi = t + 256 * j;
                int k = fi >> 5, nq = fi & 31;
                *(float4*)&Bs[k][4 * nq] = *(const float4*)&B[(size_t)(k0 + k) * n + n0 + 4 * nq];
            }
        } else {
#pragma unroll
            for (int j = 0; j < 2; ++j) {
                int fi = t + 256 * j;
                int nn = fi >> 2, kq = fi & 3;
                const float4 bv = *(const float4*)&B[(size_t)(n0 + nn) * n + k0 + 4 * kq];
                Bs[4 * kq + 0][nn] = bv.x; Bs[4 * kq + 1][nn] = bv.y;
                Bs[4 * kq + 2][nn] = bv.z; Bs[4 * kq + 3][nn] = bv.w;
            }
        }
        __syncthreads();

#pragma unroll
        for (int kk = 0; kk < BK; ++kk) {
            float a[8], b[8];
#pragma unroll
            for (int c = 0; c < 2; ++c) *(float4*)&a[4 * c] = *(const float4*)&As[kk][8 * ty + 4 * c];
#pragma unroll
            for (int c = 0; c < 2; ++c) *(float4*)&b[4 * c] = *(const float4*)&Bs[kk][8 * tx + 4 * c];
#pragma unroll
            for (int i = 0; i < 8; ++i)
#pragma unroll
                for (int j = 0; j < 8; ++j) acc[i][j] += a[i] * b[j];
        }
        __syncthreads();
    }

    // ---- epilogue
#pragma unroll
    for (int i = 0; i < 8; ++i) {
        int gi = m0 + 8 * ty + i;
        size_t rowoff = (size_t)gi * n + n0 + 8 * tx;
#pragma unroll
        for (int jc = 0; jc < 2; ++jc) {
            float4 v = make_float4(acc[i][4 * jc + 0], acc[i][4 * jc + 1],
                                   acc[i][4 * jc + 2], acc[i][4 * jc + 3]);
            if (MODE == 1) {
                float4 d = *(const float4*)&Dm[rowoff + 4 * jc];
                v = make_float4(v.x + d.x, v.y + d.y, v.z + d.z, v.w + d.w);
            } else if (MODE == 2) {
                float4 d = *(const float4*)&Dm[rowoff + 4 * jc];
                v = make_float4(d.x - v.x, d.y - v.y, d.z - v.z, d.w - v.w);
            } else if (MODE == 3) {
                int gj0 = n0 + 8 * tx + 4 * jc;
                v = make_float4(((gi == gj0 + 0) ? 2.f : 0.f) - v.x,
                                ((gi == gj0 + 1) ? 2.f : 0.f) - v.y,
                                ((gi == gj0 + 2) ? 2.f : 0.f) - v.z,
                                ((gi == gj0 + 3) ? 2.f : 0.f) - v.w);
            }
            *(float4*)&O[rowoff + 4 * jc] = v;
        }
    }
}

extern "C" void kernel_launch(void* const* d_in, const int* in_sizes, int n_in,
                              void* d_out, int out_size, void* d_ws, size_t ws_size,
                              hipStream_t stream)
{
    const int n = 2048;
    const size_t NN = (size_t)n * n;

    const float* x  = (const float*)d_in[0];
    const float* y  = (const float*)d_in[1];
    const float* u  = (const float*)d_in[2];
    const float* P  = (const float*)d_in[3];
    const float* Q  = (const float*)d_in[4];
    const float* R  = (const float*)d_in[5];
    const float* A  = (const float*)d_in[6];
    const float* B  = (const float*)d_in[7];
    const float* C  = (const float*)d_in[8];
    const float* D  = (const float*)d_in[9];
    const float* c1 = (const float*)d_in[10];
    const float* c2 = (const float*)d_in[11];

    float* out  = (float*)d_out;
    float* xout = out;       // n
    float* Pk   = out + n;   // n*n : holds Pk, becomes P_out in place

    float* ws   = (float*)d_ws;
    float* T    = ws;             // C @ Pk
    float* Py   = ws + 1 * NN;
    float* X    = ws + 2 * NN;
    float* X2   = ws + 3 * NN;
    float* E    = ws + 4 * NN;    // NS temp, then Z
    float* sv   = ws + 5 * NN;
    float* t1    = sv + 0 * n;
    float* xp    = sv + 1 * n;
    float* ob    = sv + 2 * n;
    float* ytmp  = sv + 3 * n;
    float* r     = sv + 4 * n;
    float* va    = sv + 5 * n;
    float* vb    = sv + 6 * n;
    float* zv    = sv + 7 * n;
    float* parts = sv + 8 * n;    // 16 * n
    float* scal  = sv + 24 * n;   // 4 scalars

    dim3 gblk(256);
    dim3 ggrid(BN == 128 ? 16 : 16, 16);

    // Pk = P + Q
    addmat_kernel<<<4096, gblk, 0, stream>>>(P, Q, Pk, (int)(NN / 4));

    // x_pred & residual
    matvec_kernel<<<512, gblk, 0, stream>>>(B, u, c1, t1, n);     // t1 = B u + c1
    matvec_kernel<<<512, gblk, 0, stream>>>(A, x, t1, xp, n);     // xp = A x + t1
    matvec_kernel<<<512, gblk, 0, stream>>>(D, u, c2, ob, n);     // ob = D u + c2
    matvec_kernel<<<512, gblk, 0, stream>>>(C, xp, ob, ytmp, n);  // y_est
    vec_sub_kernel<<<8, gblk, 0, stream>>>(y, ytmp, r, n);        // r = y - y_est

    // T = C @ Pk ; Py = T @ C^T + R
    gemm_kernel<0, 0, 0><<<ggrid, gblk, 0, stream>>>(C, Pk, nullptr, T, n);
    gemm_kernel<0, 1, 1><<<ggrid, gblk, 0, stream>>>(T, C, R, Py, n);

    // power iteration for lambda_max(Py)
    vec_fill_kernel<<<8, gblk, 0, stream>>>(va, 1.0f, n);
    float* pa = va; float* pb = vb;
    for (int i = 0; i < 9; ++i) {
        matvec_kernel<<<512, gblk, 0, stream>>>(Py, pa, nullptr, pb, n);
        float* tmp = pa; pa = pb; pb = tmp;
    }
    normsq_kernel<<<1, gblk, 0, stream>>>(pa, scal + 0, n);
    matvec_kernel<<<512, gblk, 0, stream>>>(Py, pa, nullptr, pb, n);
    normsq_kernel<<<1, gblk, 0, stream>>>(pb, scal + 1, n);
    alpha_kernel<<<1, 1, 0, stream>>>(scal + 0, scal + 1, scal + 2);

    // X0 = alpha * I
    eye_kernel<<<4096, gblk, 0, stream>>>(X, scal + 2, n);

    // Newton-Schulz: X <- X (2I - Py X), 7 iterations
    float* pX = X; float* pX2 = X2;
    for (int it = 0; it < 7; ++it) {
        gemm_kernel<0, 0, 3><<<ggrid, gblk, 0, stream>>>(Py, pX, nullptr, E, n); // E = 2I - Py X
        gemm_kernel<0, 0, 0><<<ggrid, gblk, 0, stream>>>(pX, E, nullptr, pX2, n); // Xn = X E
        float* tmp = pX; pX = pX2; pX2 = tmp;
    }

    // Z = X @ T  (into E)
    gemm_kernel<0, 0, 0><<<ggrid, gblk, 0, stream>>>(pX, T, nullptr, E, n);
    // zv = X @ r
    matvec_kernel<<<512, gblk, 0, stream>>>(pX, r, nullptr, zv, n);
    // x_out = xp + T^T zv
    tTv_partial_kernel<<<dim3(8, 16), gblk, 0, stream>>>(T, zv, parts, n);
    xout_final_kernel<<<8, gblk, 0, stream>>>(xp, parts, xout, n);
    // P_out = Pk - T^T Z  (in place over Pk region of d_out)
    gemm_kernel<1, 0, 2><<<ggrid, gblk, 0, stream>>>(T, E, Pk, Pk, n);
}

// Round 2
// 1251.200 us; speedup vs baseline: 3.6799x; 3.6799x over previous
//
#include <hip/hip_runtime.h>
#include <math.h>

// ---------------------------------------------------------------------------
// UKF(2048) == linear Kalman update (affine model => sigma machinery collapses):
//   xp = A x + B u + c1 ; Pk = P + Q
//   T = C Pk ; Py = T C^T + R ; G = T^T (= Pxy)
//   X ~= Py^{-1} via Newton-Schulz (4 cheap bf16 iters + 2 split-bf16 iters)
//   H = G X ; x_out = xp + H r ; P_out = Pk - H G^T
// All big GEMMs: split-bf16 MFMA (hi/lo decomposition), TN convention:
//   TN(A,B)[m][n] = sum_k A[m][k]*B[n][k]  (A row-major MxK, B row-major NxK)
// ---------------------------------------------------------------------------

typedef unsigned short u16;
typedef unsigned int u32;
typedef __attribute__((ext_vector_type(8))) short bf16x8;   // 8 x bf16 (4 VGPR)
typedef __attribute__((ext_vector_type(4))) float f32x4;

#define GN 2048
#define NNE ((size_t)GN * (size_t)GN)

__device__ __forceinline__ u16 f2bf(float f) {
    union { float f; u32 u; } x; x.f = f;
    u32 r = x.u + 0x7fffu + ((x.u >> 16) & 1u);   // RNE
    return (u16)(r >> 16);
}
__device__ __forceinline__ float bf2f(u16 b) {
    union { u32 u; float f; } x; x.u = ((u32)b) << 16;
    return x.f;
}

__device__ __forceinline__ void gload16(const u16* g, u16* l) {
    __builtin_amdgcn_global_load_lds((const __attribute__((address_space(1))) u32*)g,
                                     (__attribute__((address_space(3))) u32*)l, 16, 0, 0);
}

// ---------------- elementwise / conversion kernels ----------------

// Pk = P + Q : write fp32 (into d_out) + bf16 hi/lo
__global__ void fuse_pk(const float* __restrict__ P, const float* __restrict__ Q,
                        float* __restrict__ Pf, u16* __restrict__ Ph, u16* __restrict__ Pl)
{
    size_t i = (size_t)blockIdx.x * 256 + threadIdx.x;   // over NNE/4
    float4 p = ((const float4*)P)[i];
    float4 q = ((const float4*)Q)[i];
    float s[4] = {p.x + q.x, p.y + q.y, p.z + q.z, p.w + q.w};
    ((float4*)Pf)[i] = make_float4(s[0], s[1], s[2], s[3]);
    ushort4 h, l;
    u16* hp = (u16*)&h; u16* lp = (u16*)&l;
#pragma unroll
    for (int e = 0; e < 4; ++e) {
        u16 hb = f2bf(s[e]);
        hp[e] = hb;
        lp[e] = f2bf(s[e] - bf2f(hb));
    }
    ((ushort4*)Ph)[i] = h;
    ((ushort4*)Pl)[i] = l;
}

// hi/lo split of a fp32 matrix
__global__ void conv_hl(const float* __restrict__ S, u16* __restrict__ H, u16* __restrict__ L)
{
    size_t i = (size_t)blockIdx.x * 256 + threadIdx.x;   // over NNE/4
    float4 p = ((const float4*)S)[i];
    float s[4] = {p.x, p.y, p.z, p.w};
    ushort4 h, l;
    u16* hp = (u16*)&h; u16* lp = (u16*)&l;
#pragma unroll
    for (int e = 0; e < 4; ++e) {
        u16 hb = f2bf(s[e]);
        hp[e] = hb;
        lp[e] = f2bf(s[e] - bf2f(hb));
    }
    ((ushort4*)H)[i] = h;
    ((ushort4*)L)[i] = l;
}

// bf16-pair transpose (exact): Dh = Sh^T, Dl = Sl^T
__global__ void transpose_pair(const u16* __restrict__ Sh, const u16* __restrict__ Sl,
                               u16* __restrict__ Dh, u16* __restrict__ Dl)
{
    __shared__ u16 th[32][33];
    __shared__ u16 tl[32][33];
    int bi = blockIdx.y * 32, bj = blockIdx.x * 32;
    int r = threadIdx.x >> 5, c = threadIdx.x & 31;
    for (int rr = r; rr < 32; rr += 8) {
        th[rr][c] = Sh[(size_t)(bi + rr) * GN + bj + c];
        tl[rr][c] = Sl[(size_t)(bi + rr) * GN + bj + c];
    }
    __syncthreads();
    for (int rr = r; rr < 32; rr += 8) {
        Dh[(size_t)(bj + rr) * GN + bi + c] = th[c][rr];
        Dl[(size_t)(bj + rr) * GN + bi + c] = tl[c][rr];
    }
}

__global__ void eye_bf16(u16* __restrict__ X, const float* __restrict__ alpha)
{
    u16 a = f2bf(alpha[0]);
    for (size_t idx = (size_t)blockIdx.x * 256 + threadIdx.x; idx < NNE;
         idx += (size_t)gridDim.x * 256) {
        size_t i = idx / GN, j = idx % GN;
        X[idx] = (i == j) ? a : (u16)0;
    }
}

// ---------------- small fp32 vector kernels ----------------

__global__ void matvec_f32(const float* __restrict__ A, const float* __restrict__ v,
                           const float* __restrict__ addv, float* __restrict__ out, int n)
{
    int wid = threadIdx.x >> 6, lane = threadIdx.x & 63;
    int row = blockIdx.x * 4 + wid;
    if (row >= n) return;
    const float* arow = A + (size_t)row * n;
    float s = 0.f;
    for (int j = lane; j < n; j += 64) s += arow[j] * v[j];
#pragma unroll
    for (int off = 32; off > 0; off >>= 1) s += __shfl_down(s, off);
    if (lane == 0) out[row] = s + (addv ? addv[row] : 0.f);
}

// out[row] = sum_j (hi+lo)[row][j]*v[j] + addv[row]
__global__ void matvec_hl(const u16* __restrict__ Mh, const u16* __restrict__ Ml,
                          const float* __restrict__ v, const float* __restrict__ addv,
                          float* __restrict__ out, int n)
{
    int wid = threadIdx.x >> 6, lane = threadIdx.x & 63;
    int row = blockIdx.x * 4 + wid;
    if (row >= n) return;
    const u16* hr = Mh + (size_t)row * n;
    const u16* lr = Ml ? Ml + (size_t)row * n : (const u16*)0;
    float s = 0.f;
    for (int j = lane * 8; j < n; j += 512) {
        uint4 hb = *(const uint4*)&hr[j];
        float4 v0 = *(const float4*)&v[j];
        float4 v1 = *(const float4*)&v[j + 4];
        u32 hw[4] = {hb.x, hb.y, hb.z, hb.w};
        float m[8];
#pragma unroll
        for (int e = 0; e < 4; ++e) {
            m[2 * e]     = bf2f((u16)(hw[e] & 0xffffu));
            m[2 * e + 1] = bf2f((u16)(hw[e] >> 16));
        }
        if (lr) {
            uint4 lb = *(const uint4*)&lr[j];
            u32 lw[4] = {lb.x, lb.y, lb.z, lb.w};
#pragma unroll
            for (int e = 0; e < 4; ++e) {
                m[2 * e]     += bf2f((u16)(lw[e] & 0xffffu));
                m[2 * e + 1] += bf2f((u16)(lw[e] >> 16));
            }
        }
        s += m[0] * v0.x + m[1] * v0.y + m[2] * v0.z + m[3] * v0.w
           + m[4] * v1.x + m[5] * v1.y + m[6] * v1.z + m[7] * v1.w;
    }
#pragma unroll
    for (int off = 32; off > 0; off >>= 1) s += __shfl_down(s, off);
    if (lane == 0) out[row] = s + (addv ? addv[row] : 0.f);
}

__global__ void vec_sub(const float* __restrict__ a, const float* __restrict__ b,
                        float* __restrict__ o, int n)
{
    int i = blockIdx.x * 256 + threadIdx.x;
    if (i < n) o[i] = a[i] - b[i];
}

__global__ void vec_fill(float* __restrict__ o, float val, int n)
{
    int i = blockIdx.x * 256 + threadIdx.x;
    if (i < n) o[i] = val;
}

__global__ void normsq(const float* __restrict__ v, float* __restrict__ out, int n)
{
    __shared__ float sm[256];
    float s = 0.f;
    for (int i = threadIdx.x; i < n; i += 256) { float x = v[i]; s += x * x; }
    sm[threadIdx.x] = s;
    __syncthreads();
    for (int w = 128; w > 0; w >>= 1) {
        if (threadIdx.x < w) sm[threadIdx.x] += sm[threadIdx.x + w];
        __syncthreads();
    }
    if (threadIdx.x == 0) out[0] = sm[0];
}

__global__ void alpha_k(const float* __restrict__ ns9, const float* __restrict__ ns10,
                        float* __restrict__ alpha)
{
    float lam = sqrtf(ns10[0] / ns9[0]);
    alpha[0] = 2.0f / (1.3f * lam);
}

// ---------------- MFMA TN-GEMM (m97 structure) ----------------
// O = op(MODE){ sum_s A_s * B_s^T } over nseg bf16 segment pairs.
// MODE 0: O = S ; 1: O = S + Dm ; 2: O = Dm - S ; 3: O = 2I - S
// WHI/WLO/WF32: which outputs to write (bf16 hi, bf16 lo, fp32).
template <int MODE, int WHI, int WLO, int WF32>
__global__ __launch_bounds__(256) void mfma_gemm(
    const u16* A0, const u16* B0, const u16* A1, const u16* B1,
    const u16* A2, const u16* B2, int nseg,
    const float* Dm, float* Of, u16* Ohi, u16* Olo)
{
    __shared__ __align__(16) u16 As[128 * 32];
    __shared__ __align__(16) u16 Bs[128 * 32];
    const int t = threadIdx.x;
    const int wid = t >> 6, l = t & 63;
    const int wr = wid >> 1, wc = wid & 1;            // 2x2 waves, 64x64 each
    const int m0 = blockIdx.y * 128, n0 = blockIdx.x * 128;

    f32x4 acc[4][4] = {};

    const int srow = l >> 2;                // staging row within 16-row chunk
    const int scol = (l & 3) * 8;           // staging k-offset (8 bf16 = 16B)
    u16* AsW = As + wid * 512;              // per-wave linear 1KB chunk
    u16* BsW = Bs + wid * 512;
    const int lrow = l & 15;
    const int lko  = (l >> 4) * 8;

    for (int s = 0; s < nseg; ++s) {
        const u16* Ap = (s == 0) ? A0 : ((s == 1) ? A1 : A2);
        const u16* Bp = (s == 0) ? B0 : ((s == 1) ? B1 : B2);
        const u16* gA0 = Ap + (size_t)(m0 + wid * 16 + srow) * GN + scol;
        const u16* gB0 = Bp + (size_t)(n0 + wid * 16 + srow) * GN + scol;
        const u16* gA1 = gA0 + (size_t)64 * GN;
        const u16* gB1 = gB0 + (size_t)64 * GN;
        for (int k0 = 0; k0 < GN; k0 += 32) {
            __syncthreads();                 // LDS consumed by previous step
            gload16(gA0 + k0, AsW);
            gload16(gA1 + k0, AsW + 2048);
            gload16(gB0 + k0, BsW);
            gload16(gB1 + k0, BsW + 2048);
            __syncthreads();                 // drains vmcnt before barrier
            bf16x8 af[4], bq[4];
#pragma unroll
            for (int mi = 0; mi < 4; ++mi)
                af[mi] = *(const bf16x8*)&As[(wr * 64 + mi * 16 + lrow) * 32 + lko];
#pragma unroll
            for (int ni = 0; ni < 4; ++ni)
                bq[ni] = *(const bf16x8*)&Bs[(wc * 64 + ni * 16 + lrow) * 32 + lko];
#pragma unroll
            for (int mi = 0; mi < 4; ++mi)
#pragma unroll
                for (int ni = 0; ni < 4; ++ni)
                    acc[mi][ni] = __builtin_amdgcn_mfma_f32_16x16x32_bf16(
                        af[mi], bq[ni], acc[mi][ni], 0, 0, 0);
        }
    }

    // epilogue: D frag mapping col = l&15, row = (l>>4)*4 + r
#pragma unroll
    for (int mi = 0; mi < 4; ++mi) {
#pragma unroll
        for (int r = 0; r < 4; ++r) {
            int gm = m0 + wr * 64 + mi * 16 + (l >> 4) * 4 + r;
            size_t rowo = (size_t)gm * GN;
#pragma unroll
            for (int ni = 0; ni < 4; ++ni) {
                int gn = n0 + wc * 64 + ni * 16 + lrow;
                float v = acc[mi][ni][r];
                if (MODE == 1) v = v + Dm[rowo + gn];
                else if (MODE == 2) v = Dm[rowo + gn] - v;
                else if (MODE == 3) v = ((gm == gn) ? 2.0f : 0.0f) - v;
                if (WF32) Of[rowo + gn] = v;
                if (WHI) {
                    u16 h = f2bf(v);
                    Ohi[rowo + gn] = h;
                    if (WLO) Olo[rowo + gn] = f2bf(v - bf2f(h));
                }
            }
        }
    }
}

// ---------------- host ----------------

extern "C" void kernel_launch(void* const* d_in, const int* in_sizes, int n_in,
                              void* d_out, int out_size, void* d_ws, size_t ws_size,
                              hipStream_t stream)
{
    const int n = GN;
    const float* x  = (const float*)d_in[0];
    const float* y  = (const float*)d_in[1];
    const float* u  = (const float*)d_in[2];
    const float* P  = (const float*)d_in[3];
    const float* Q  = (const float*)d_in[4];
    const float* R  = (const float*)d_in[5];
    const float* A  = (const float*)d_in[6];
    const float* B  = (const float*)d_in[7];
    const float* C  = (const float*)d_in[8];
    const float* D  = (const float*)d_in[9];
    const float* c1 = (const float*)d_in[10];
    const float* c2 = (const float*)d_in[11];

    float* out  = (float*)d_out;
    float* xout = out;          // n
    float* Pf   = out + n;      // n*n fp32: Pk, becomes P_out in place

    // workspace: 10 bf16 NxN slots (8 MB each) + small fp32 vectors
    u16* wsu = (u16*)d_ws;
    u16* S0 = wsu + 0 * NNE;  // C_hi  -> G_hi
    u16* S1 = wsu + 1 * NNE;  // C_lo  -> G_lo
    u16* S2 = wsu + 2 * NNE;  // Pk_hi -> Py_hi
    u16* S3 = wsu + 3 * NNE;  // Pk_lo -> Py_lo
    u16* S4 = wsu + 4 * NNE;  // T_hi  -> Xa_hi
    u16* S5 = wsu + 5 * NNE;  // T_lo  -> Xa_lo
    u16* S6 = wsu + 6 * NNE;  // Xb_hi
    u16* S7 = wsu + 7 * NNE;  // Xb_lo
    u16* S8 = wsu + 8 * NNE;  // E_hi  -> H_hi
    u16* S9 = wsu + 9 * NNE;  // E_lo  -> H_lo
    float* vecs = (float*)(wsu + 10 * NNE);
    float* t1   = vecs + 0 * n;
    float* xp   = vecs + 1 * n;
    float* ob   = vecs + 2 * n;
    float* ytmp = vecs + 3 * n;
    float* rr   = vecs + 4 * n;
    float* va   = vecs + 5 * n;
    float* vb   = vecs + 6 * n;
    float* scal = vecs + 7 * n;

    dim3 blk(256);
    dim3 gg(16, 16);

    // Pk = P + Q (fp32 + hi/lo) ; C -> hi/lo
    fuse_pk<<<4096, blk, 0, stream>>>(P, Q, Pf, S2, S3);
    conv_hl<<<4096, blk, 0, stream>>>(C, S0, S1);

    // xp = A x + B u + c1 ; r = y - (C xp + D u + c2)
    matvec_f32<<<512, blk, 0, stream>>>(B, u, c1, t1, n);
    matvec_f32<<<512, blk, 0, stream>>>(A, x, t1, xp, n);
    matvec_f32<<<512, blk, 0, stream>>>(D, u, c2, ob, n);
    matvec_f32<<<512, blk, 0, stream>>>(C, xp, ob, ytmp, n);
    vec_sub<<<8, blk, 0, stream>>>(y, ytmp, rr, n);

    // T = TN(C, Pk)  (split)  -> S4,S5
    mfma_gemm<0, 1, 1, 0><<<gg, blk, 0, stream>>>(S0, S2, S0, S3, S1, S2, 3,
                                                  nullptr, nullptr, S4, S5);
    // Py = TN(T, C) + R  (split) -> S2,S3   (Pk bf16 dead)
    mfma_gemm<1, 1, 1, 0><<<gg, blk, 0, stream>>>(S4, S0, S4, S1, S5, S0, 3,
                                                  R, nullptr, S2, S3);
    // G = T^T -> S0,S1  (C bf16 dead)
    transpose_pair<<<dim3(64, 64), blk, 0, stream>>>(S4, S5, S0, S1);

    // power iteration on Py_hi for lambda_max -> alpha = 2/(1.3*lam)
    vec_fill<<<8, blk, 0, stream>>>(va, 1.0f, n);
    float* pa = va; float* pb = vb;
    for (int i = 0; i < 9; ++i) {
        matvec_hl<<<512, blk, 0, stream>>>(S2, nullptr, pa, nullptr, pb, n);
        float* tmp = pa; pa = pb; pb = tmp;
    }
    normsq<<<1, blk, 0, stream>>>(pa, scal + 0, n);
    matvec_hl<<<512, blk, 0, stream>>>(S2, nullptr, pa, nullptr, pb, n);
    normsq<<<1, blk, 0, stream>>>(pb, scal + 1, n);
    alpha_k<<<1, 1, 0, stream>>>(scal + 0, scal + 1, scal + 2);

    // X0 = alpha * I (bf16 hi) -> S4 (T dead)
    eye_bf16<<<4096, blk, 0, stream>>>(S4, scal + 2);

    // Newton-Schulz. X symmetric, Py symmetric => all TN-compatible.
    u16 *ch = S4, *cl = S5, *oh = S6, *ol = S7;
    // 4 cheap (hi-only) iterations
    for (int it = 0; it < 4; ++it) {
        mfma_gemm<3, 1, 0, 0><<<gg, blk, 0, stream>>>(ch, S2, nullptr, nullptr, nullptr, nullptr, 1,
                                                      nullptr, nullptr, S8, nullptr); // E = 2I - X Py
        mfma_gemm<0, 1, 0, 0><<<gg, blk, 0, stream>>>(S8, ch, nullptr, nullptr, nullptr, nullptr, 1,
                                                      nullptr, nullptr, oh, nullptr); // Xn = E X
        u16* th_ = ch; ch = oh; oh = th_;
        u16* tl_ = cl; cl = ol; ol = tl_;
    }
    // precise iteration 1 (X has hi only)
    mfma_gemm<3, 1, 1, 0><<<gg, blk, 0, stream>>>(ch, S2, ch, S3, nullptr, nullptr, 2,
                                                  nullptr, nullptr, S8, S9);
    mfma_gemm<0, 1, 1, 0><<<gg, blk, 0, stream>>>(S8, ch, S9, ch, nullptr, nullptr, 2,
                                                  nullptr, nullptr, oh, ol);
    { u16* th_ = ch; ch = oh; oh = th_; u16* tl_ = cl; cl = ol; ol = tl_; }
    // precise iteration 2 (X has hi+lo)
    mfma_gemm<3, 1, 1, 0><<<gg, blk, 0, stream>>>(ch, S2, ch, S3, cl, S2, 3,
                                                  nullptr, nullptr, S8, S9);
    mfma_gemm<0, 1, 1, 0><<<gg, blk, 0, stream>>>(S8, ch, S8, cl, S9, ch, 3,
                                                  nullptr, nullptr, oh, ol);
    { u16* th_ = ch; ch = oh; oh = th_; u16* tl_ = cl; cl = ol; ol = tl_; }

    // H = TN(G, X) (split) -> S8,S9
    mfma_gemm<0, 1, 1, 0><<<gg, blk, 0, stream>>>(S0, ch, S0, cl, S1, ch, 3,
                                                  nullptr, nullptr, S8, S9);
    // x_out = xp + H r
    matvec_hl<<<512, blk, 0, stream>>>(S8, S9, rr, xp, xout, n);
    // P_out = Pk - TN(H, G) (split) -> Pf in place
    mfma_gemm<2, 0, 0, 1><<<gg, blk, 0, stream>>>(S8, S0, S8, S1, S9, S0, 3,
                                                  Pf, Pf, nullptr, nullptr);
}

// Round 3
// 923.199 us; speedup vs baseline: 4.9874x; 1.3553x over previous
//
#include <hip/hip_runtime.h>
#include <math.h>

// ---------------------------------------------------------------------------
// UKF(2048) == linear Kalman update (affine model => sigma machinery collapses):
//   xp = A x + B u + c1 ; Pk = P + Q
//   T = C Pk ; Py = T C^T + R ; G = T^T (= Pxy)
//   X ~= Py^{-1} via Newton-Schulz (4 bf16-hi iters + 1 exact-split iter)
//   P_out = Pk - (G X) G^T
//   z = Py^{-1} r via X-preconditioned iterative refinement (matvec only)
//   x_out = xp + G z
// Split-bf16 MFMA GEMMs, TN convention: TN(A,B)[m][n] = sum_k A[m][k]*B[n][k]
// GEMM kernel: 128x128 tile, 8 waves (2x4), BK=64, global_load_lds w/ XOR
// swizzle (pre-swizzled global source, linear LDS dest, swizzled reads).
// ---------------------------------------------------------------------------

typedef unsigned short u16;
typedef unsigned int u32;
typedef __attribute__((ext_vector_type(8))) short bf16x8;
typedef __attribute__((ext_vector_type(4))) float f32x4;

#define GN 2048
#define NNE ((size_t)GN * (size_t)GN)

__device__ __forceinline__ u16 f2bf(float f) {
    union { float f; u32 u; } x; x.f = f;
    u32 r = x.u + 0x7fffu + ((x.u >> 16) & 1u);   // RNE
    return (u16)(r >> 16);
}
__device__ __forceinline__ float bf2f(u16 b) {
    union { u32 u; float f; } x; x.u = ((u32)b) << 16;
    return x.f;
}

__device__ __forceinline__ void gload16(const u16* g, u16* l) {
    __builtin_amdgcn_global_load_lds((const __attribute__((address_space(1))) u32*)g,
                                     (__attribute__((address_space(3))) u32*)l, 16, 0, 0);
}

// ---------------- elementwise / conversion ----------------

__global__ void fuse_pk(const float* __restrict__ P, const float* __restrict__ Q,
                        float* __restrict__ Pf, u16* __restrict__ Ph, u16* __restrict__ Pl)
{
    size_t i = (size_t)blockIdx.x * 256 + threadIdx.x;   // over NNE/4
    float4 p = ((const float4*)P)[i];
    float4 q = ((const float4*)Q)[i];
    float s[4] = {p.x + q.x, p.y + q.y, p.z + q.z, p.w + q.w};
    ((float4*)Pf)[i] = make_float4(s[0], s[1], s[2], s[3]);
    ushort4 h, l;
    u16* hp = (u16*)&h; u16* lp = (u16*)&l;
#pragma unroll
    for (int e = 0; e < 4; ++e) {
        u16 hb = f2bf(s[e]);
        hp[e] = hb;
        lp[e] = f2bf(s[e] - bf2f(hb));
    }
    ((ushort4*)Ph)[i] = h;
    ((ushort4*)Pl)[i] = l;
}

__global__ void conv_hl(const float* __restrict__ S, u16* __restrict__ H, u16* __restrict__ L)
{
    size_t i = (size_t)blockIdx.x * 256 + threadIdx.x;   // over NNE/4
    float4 p = ((const float4*)S)[i];
    float s[4] = {p.x, p.y, p.z, p.w};
    ushort4 h, l;
    u16* hp = (u16*)&h; u16* lp = (u16*)&l;
#pragma unroll
    for (int e = 0; e < 4; ++e) {
        u16 hb = f2bf(s[e]);
        hp[e] = hb;
        lp[e] = f2bf(s[e] - bf2f(hb));
    }
    ((ushort4*)H)[i] = h;
    ((ushort4*)L)[i] = l;
}

__global__ void transpose_pair(const u16* __restrict__ Sh, const u16* __restrict__ Sl,
                               u16* __restrict__ Dh, u16* __restrict__ Dl)
{
    __shared__ u16 th[32][33];
    __shared__ u16 tl[32][33];
    int bi = blockIdx.y * 32, bj = blockIdx.x * 32;
    int r = threadIdx.x >> 5, c = threadIdx.x & 31;
    for (int rr = r; rr < 32; rr += 8) {
        th[rr][c] = Sh[(size_t)(bi + rr) * GN + bj + c];
        tl[rr][c] = Sl[(size_t)(bi + rr) * GN + bj + c];
    }
    __syncthreads();
    for (int rr = r; rr < 32; rr += 8) {
        Dh[(size_t)(bj + rr) * GN + bi + c] = th[c][rr];
        Dl[(size_t)(bj + rr) * GN + bi + c] = tl[c][rr];
    }
}

__global__ void eye_bf16(u16* __restrict__ X, const float* __restrict__ alpha)
{
    u16 a = f2bf(alpha[0]);
    for (size_t idx = (size_t)blockIdx.x * 256 + threadIdx.x; idx < NNE;
         idx += (size_t)gridDim.x * 256) {
        size_t i = idx / GN, j = idx % GN;
        X[idx] = (i == j) ? a : (u16)0;
    }
}

// ---------------- vector kernels ----------------

__global__ void matvec_f32(const float* __restrict__ A, const float* __restrict__ v,
                           const float* __restrict__ addv, float* __restrict__ out, int n)
{
    int wid = threadIdx.x >> 6, lane = threadIdx.x & 63;
    int row = blockIdx.x * 4 + wid;
    if (row >= n) return;
    const float* arow = A + (size_t)row * n;
    float s = 0.f;
    for (int j = lane; j < n; j += 64) s += arow[j] * v[j];
#pragma unroll
    for (int off = 32; off > 0; off >>= 1) s += __shfl_down(s, off);
    if (lane == 0) out[row] = s + (addv ? addv[row] : 0.f);
}

// out[row] = (addv ? addv[row] : 0) + sign * dot((hi+lo)[row,:], v)
__global__ void matvec_hl(const u16* __restrict__ Mh, const u16* __restrict__ Ml,
                          const float* __restrict__ v, const float* __restrict__ addv,
                          float* __restrict__ out, float sign, int n)
{
    int wid = threadIdx.x >> 6, lane = threadIdx.x & 63;
    int row = blockIdx.x * 4 + wid;
    if (row >= n) return;
    const u16* hr = Mh + (size_t)row * n;
    const u16* lr = Ml ? Ml + (size_t)row * n : (const u16*)0;
    float s = 0.f;
    for (int j = lane * 8; j < n; j += 512) {
        uint4 hb = *(const uint4*)&hr[j];
        float4 v0 = *(const float4*)&v[j];
        float4 v1 = *(const float4*)&v[j + 4];
        u32 hw[4] = {hb.x, hb.y, hb.z, hb.w};
        float m[8];
#pragma unroll
        for (int e = 0; e < 4; ++e) {
            m[2 * e]     = bf2f((u16)(hw[e] & 0xffffu));
            m[2 * e + 1] = bf2f((u16)(hw[e] >> 16));
        }
        if (lr) {
            uint4 lb = *(const uint4*)&lr[j];
            u32 lw[4] = {lb.x, lb.y, lb.z, lb.w};
#pragma unroll
            for (int e = 0; e < 4; ++e) {
                m[2 * e]     += bf2f((u16)(lw[e] & 0xffffu));
                m[2 * e + 1] += bf2f((u16)(lw[e] >> 16));
            }
        }
        s += m[0] * v0.x + m[1] * v0.y + m[2] * v0.z + m[3] * v0.w
           + m[4] * v1.x + m[5] * v1.y + m[6] * v1.z + m[7] * v1.w;
    }
#pragma unroll
    for (int off = 32; off > 0; off >>= 1) s += __shfl_down(s, off);
    if (lane == 0) out[row] = (addv ? addv[row] : 0.f) + sign * s;
}

__global__ void vec_sub(const float* __restrict__ a, const float* __restrict__ b,
                        float* __restrict__ o, int n)
{
    int i = blockIdx.x * 256 + threadIdx.x;
    if (i < n) o[i] = a[i] - b[i];
}

__global__ void vec_fill(float* __restrict__ o, float val, int n)
{
    int i = blockIdx.x * 256 + threadIdx.x;
    if (i < n) o[i] = val;
}

__global__ void normsq(const float* __restrict__ v, float* __restrict__ out, int n)
{
    __shared__ float sm[256];
    float s = 0.f;
    for (int i = threadIdx.x; i < n; i += 256) { float x = v[i]; s += x * x; }
    sm[threadIdx.x] = s;
    __syncthreads();
    for (int w = 128; w > 0; w >>= 1) {
        if (threadIdx.x < w) sm[threadIdx.x] += sm[threadIdx.x + w];
        __syncthreads();
    }
    if (threadIdx.x == 0) out[0] = sm[0];
}

__global__ void alpha_k(const float* __restrict__ ns9, const float* __restrict__ ns10,
                        float* __restrict__ alpha)
{
    float lam = sqrtf(ns10[0] / ns9[0]);
    alpha[0] = 2.0f / (1.3f * lam);
}

// ---------------- MFMA TN-GEMM: 128x128 tile, 8 waves, BK=64, swizzled ----------------
// O = op(MODE){ sum_s A_s * B_s^T } ; MODE 0: S ; 1: S+Dm ; 2: Dm-S ; 3: 2I-S
template <int MODE, int WHI, int WLO, int WF32>
__global__ __launch_bounds__(512, 2) void mfma_gemm(
    const u16* A0, const u16* B0, const u16* A1, const u16* B1,
    const u16* A2, const u16* B2, int nseg,
    const float* Dm, float* Of, u16* Ohi, u16* Olo)
{
    __shared__ __align__(16) u16 As[128 * 64];
    __shared__ __align__(16) u16 Bs[128 * 64];
    const int t = threadIdx.x;
    const int wid = t >> 6, l = t & 63;
    const int wr = wid >> 2, wc = wid & 3;            // 2x4 waves, tile 64x32
    const int m0 = blockIdx.y * 128, n0 = blockIdx.x * 128;

    f32x4 acc[4][2] = {};

    // staging: wave w covers rows [w*16, w*16+16); instr i covers 8 rows.
    // LDS is linear; swizzle applied by permuting the GLOBAL source column:
    // phys content(row, slot) = global col slot^(row&7); row&7 == l>>3 here.
    const int srow = l >> 3;                            // 0..7
    const int scol = (((l & 7) ^ srow) << 3);           // source col, elements
    u16* AsW0 = As + wid * 1024;
    u16* AsW1 = AsW0 + 512;
    u16* BsW0 = Bs + wid * 1024;
    u16* BsW1 = BsW0 + 512;

    // read side: logical slot (ks*4 + l>>4) at row with row&7 == l&7
    const int lrow = l & 15;
    const int lq = l >> 4;
    const int lb = l & 7;
    int aoff[4][2], boff[2][2];
#pragma unroll
    for (int mi = 0; mi < 4; ++mi) {
        int r = wr * 64 + mi * 16 + lrow;
#pragma unroll
        for (int ks = 0; ks < 2; ++ks)
            aoff[mi][ks] = r * 64 + (((ks * 4 + lq) ^ lb) << 3);
    }
#pragma unroll
    for (int ni = 0; ni < 2; ++ni) {
        int r = wc * 32 + ni * 16 + lrow;
#pragma unroll
        for (int ks = 0; ks < 2; ++ks)
            boff[ni][ks] = r * 64 + (((ks * 4 + lq) ^ lb) << 3);
    }

    for (int s = 0; s < nseg; ++s) {
        const u16* Ap = (s == 0) ? A0 : ((s == 1) ? A1 : A2);
        const u16* Bp = (s == 0) ? B0 : ((s == 1) ? B1 : B2);
        const u16* gA = Ap + (size_t)(m0 + wid * 16 + srow) * GN + scol;
        const u16* gB = Bp + (size_t)(n0 + wid * 16 + srow) * GN + scol;
        for (int k0 = 0; k0 < GN; k0 += 64) {
            __syncthreads();                  // previous step's reads done
            gload16(gA + k0, AsW0);
            gload16(gA + (size_t)8 * GN + k0, AsW1);
            gload16(gB + k0, BsW0);
            gload16(gB + (size_t)8 * GN + k0, BsW1);
            __syncthreads();                  // drains vmcnt, data visible
#pragma unroll
            for (int ks = 0; ks < 2; ++ks) {
                bf16x8 af[4], bq[2];
#pragma unroll
                for (int mi = 0; mi < 4; ++mi)
                    af[mi] = *(const bf16x8*)&As[aoff[mi][ks]];
#pragma unroll
                for (int ni = 0; ni < 2; ++ni)
                    bq[ni] = *(const bf16x8*)&Bs[boff[ni][ks]];
#pragma unroll
                for (int mi = 0; mi < 4; ++mi)
#pragma unroll
                    for (int ni = 0; ni < 2; ++ni)
                        acc[mi][ni] = __builtin_amdgcn_mfma_f32_16x16x32_bf16(
                            af[mi], bq[ni], acc[mi][ni], 0, 0, 0);
            }
        }
    }

    // epilogue: C/D frag mapping col = l&15, row = (l>>4)*4 + r
#pragma unroll
    for (int mi = 0; mi < 4; ++mi) {
#pragma unroll
        for (int r = 0; r < 4; ++r) {
            int gm = m0 + wr * 64 + mi * 16 + lq * 4 + r;
            size_t rowo = (size_t)gm * GN;
#pragma unroll
            for (int ni = 0; ni < 2; ++ni) {
                int gn = n0 + wc * 32 + ni * 16 + lrow;
                float v = acc[mi][ni][r];
                if (MODE == 1) v = v + Dm[rowo + gn];
                else if (MODE == 2) v = Dm[rowo + gn] - v;
                else if (MODE == 3) v = ((gm == gn) ? 2.0f : 0.0f) - v;
                if (WF32) Of[rowo + gn] = v;
                if (WHI) {
                    u16 h = f2bf(v);
                    Ohi[rowo + gn] = h;
                    if (WLO) Olo[rowo + gn] = f2bf(v - bf2f(h));
                }
            }
        }
    }
}

// ---------------- host ----------------

extern "C" void kernel_launch(void* const* d_in, const int* in_sizes, int n_in,
                              void* d_out, int out_size, void* d_ws, size_t ws_size,
                              hipStream_t stream)
{
    const int n = GN;
    const float* x  = (const float*)d_in[0];
    const float* y  = (const float*)d_in[1];
    const float* u  = (const float*)d_in[2];
    const float* P  = (const float*)d_in[3];
    const float* Q  = (const float*)d_in[4];
    const float* R  = (const float*)d_in[5];
    const float* A  = (const float*)d_in[6];
    const float* B  = (const float*)d_in[7];
    const float* C  = (const float*)d_in[8];
    const float* D  = (const float*)d_in[9];
    const float* c1 = (const float*)d_in[10];
    const float* c2 = (const float*)d_in[11];

    float* out  = (float*)d_out;
    float* xout = out;          // n
    float* Pf   = out + n;      // n*n fp32: Pk, becomes P_out in place

    // 10 bf16 NxN slots (8.4 MB each) + small fp32 vectors
    u16* wsu = (u16*)d_ws;
    u16* S0 = wsu + 0 * NNE;  // C_hi  -> G_hi
    u16* S1 = wsu + 1 * NNE;  // C_lo  -> G_lo
    u16* S2 = wsu + 2 * NNE;  // Pk_hi -> Xa_hi
    u16* S3 = wsu + 3 * NNE;  // Pk_lo
    u16* S4 = wsu + 4 * NNE;  // T_hi  -> Xb_hi (final X_hi)
    u16* S5 = wsu + 5 * NNE;  // T_lo  -> Xb_lo (final X_lo)
    u16* S6 = wsu + 6 * NNE;  // Py_hi
    u16* S7 = wsu + 7 * NNE;  // Py_lo
    u16* S8 = wsu + 8 * NNE;  // E_hi  -> H_hi
    u16* S9 = wsu + 9 * NNE;  // E_lo  -> H_lo
    float* vecs = (float*)(wsu + 10 * NNE);
    float* t1   = vecs + 0 * n;
    float* xp   = vecs + 1 * n;
    float* ob   = vecs + 2 * n;
    float* ytmp = vecs + 3 * n;
    float* rr   = vecs + 4 * n;
    float* va   = vecs + 5 * n;
    float* vb   = vecs + 6 * n;
    float* z0   = vecs + 7 * n;
    float* z1   = vecs + 8 * n;
    float* rho  = vecs + 9 * n;
    float* scal = vecs + 10 * n;

    dim3 blk256(256), blk512(512);
    dim3 gg(16, 16);

    // Pk = P + Q (fp32 into d_out + hi/lo) ; C -> hi/lo
    fuse_pk<<<4096, blk256, 0, stream>>>(P, Q, Pf, S2, S3);
    conv_hl<<<4096, blk256, 0, stream>>>(C, S0, S1);

    // xp = A x + B u + c1 ; rr = y - (C xp + D u + c2)
    matvec_f32<<<512, blk256, 0, stream>>>(B, u, c1, t1, n);
    matvec_f32<<<512, blk256, 0, stream>>>(A, x, t1, xp, n);
    matvec_f32<<<512, blk256, 0, stream>>>(D, u, c2, ob, n);
    matvec_f32<<<512, blk256, 0, stream>>>(C, xp, ob, ytmp, n);
    vec_sub<<<8, blk256, 0, stream>>>(y, ytmp, rr, n);

    // T = TN(C, Pk) (full split) -> S4/S5
    mfma_gemm<0, 1, 1, 0><<<gg, blk512, 0, stream>>>(S0, S2, S0, S3, S1, S2, 3,
                                                     nullptr, nullptr, S4, S5);
    // Py = TN(T, C) + R (full split) -> S6/S7
    mfma_gemm<1, 1, 1, 0><<<gg, blk512, 0, stream>>>(S4, S0, S4, S1, S5, S0, 3,
                                                     R, nullptr, S6, S7);
    // G = T^T -> S0/S1 (C bf16 dead)
    transpose_pair<<<dim3(64, 64), blk256, 0, stream>>>(S4, S5, S0, S1);

    // power iteration for lambda_max(Py) -> alpha
    vec_fill<<<8, blk256, 0, stream>>>(va, 1.0f, n);
    float* pa = va; float* pb = vb;
    for (int i = 0; i < 9; ++i) {
        matvec_hl<<<512, blk256, 0, stream>>>(S6, nullptr, pa, nullptr, pb, 1.0f, n);
        float* tmp = pa; pa = pb; pb = tmp;
    }
    normsq<<<1, blk256, 0, stream>>>(pa, scal + 0, n);
    matvec_hl<<<512, blk256, 0, stream>>>(S6, nullptr, pa, nullptr, pb, 1.0f, n);
    normsq<<<1, blk256, 0, stream>>>(pb, scal + 1, n);
    alpha_k<<<1, 1, 0, stream>>>(scal + 0, scal + 1, scal + 2);

    // X0 = alpha*I (hi) -> S2 (Pk bf16 dead after T GEMM)
    eye_bf16<<<4096, blk256, 0, stream>>>(S2, scal + 2);

    // 4 cheap NS iterations (hi-only), X alternates S2 <-> S4
    u16* ch = S2; u16* oh = S4;
    for (int it = 0; it < 4; ++it) {
        mfma_gemm<3, 1, 0, 0><<<gg, blk512, 0, stream>>>(ch, S6, nullptr, nullptr, nullptr, nullptr, 1,
                                                         nullptr, nullptr, S8, nullptr); // E = 2I - X Py
        mfma_gemm<0, 1, 0, 0><<<gg, blk512, 0, stream>>>(S8, ch, nullptr, nullptr, nullptr, nullptr, 1,
                                                         nullptr, nullptr, oh, nullptr); // Xn = E X
        u16* tmp = ch; ch = oh; oh = tmp;
    }
    // one exact-split NS iteration: X(hi) -> X(hi/lo) in S4/S5   (ch==S2 here)
    mfma_gemm<3, 1, 1, 0><<<gg, blk512, 0, stream>>>(ch, S6, ch, S7, nullptr, nullptr, 2,
                                                     nullptr, nullptr, S8, S9);          // E = 2I - X*Py(full)
    mfma_gemm<0, 1, 1, 0><<<gg, blk512, 0, stream>>>(S8, ch, S9, ch, nullptr, nullptr, 2,
                                                     nullptr, nullptr, S4, S5);          // Xn = E(full)*X

    // H = TN(G, X) (split) -> S8/S9
    mfma_gemm<0, 1, 1, 0><<<gg, blk512, 0, stream>>>(S0, S4, S0, S5, S1, S4, 3,
                                                     nullptr, nullptr, S8, S9);
    // P_out = Pk - TN(H, G) (split) -> Pf in place
    mfma_gemm<2, 0, 0, 1><<<gg, blk512, 0, stream>>>(S8, S0, S8, S1, S9, S0, 3,
                                                     Pf, Pf, nullptr, nullptr);

    // z = Py^{-1} rr by X-preconditioned iterative refinement (2 steps)
    matvec_hl<<<512, blk256, 0, stream>>>(S4, S5, rr, nullptr, z0, 1.0f, n);   // z0 = X r
    matvec_hl<<<512, blk256, 0, stream>>>(S6, S7, z0, rr, rho, -1.0f, n);      // rho = r - Py z0
    matvec_hl<<<512, blk256, 0, stream>>>(S4, S5, rho, z0, z1, 1.0f, n);       // z1 = z0 + X rho
    matvec_hl<<<512, blk256, 0, stream>>>(S6, S7, z1, rr, rho, -1.0f, n);      // rho = r - Py z1
    matvec_hl<<<512, blk256, 0, stream>>>(S4, S5, rho, z1, z0, 1.0f, n);       // z2 = z1 + X rho
    // x_out = xp + G z2
    matvec_hl<<<512, blk256, 0, stream>>>(S0, S1, z0, xp, xout, 1.0f, n);
}